// Round 10
// baseline (781.476 us; speedup 1.0000x reference)
//
#include <hip/hip_runtime.h>
#include <hip/hip_bf16.h>
#include <cstdint>
#include <cstddef>

// Problem constants
#define NB 2048      // batch tokens
#define NM 4         // modalities
#define DM 1024      // model dim
#define NE 8         // experts
#define NH 4096      // expert hidden
#define CAPP 4352    // padded (b,expert)-pair capacity: 4096 + 8*32
#define NTIL 136     // CAPP/32 pair-tiles (128 gathered rows each)

typedef __attribute__((ext_vector_type(8))) short bf16x8;
typedef __attribute__((ext_vector_type(4))) float f32x4;

__device__ __forceinline__ void gload16(const void* g, void* l) {
  // async global->LDS, 16B/lane; LDS dest = wave-uniform base + lane*16
  __builtin_amdgcn_global_load_lds((const __attribute__((address_space(1))) void*)g,
                                   (__attribute__((address_space(3))) void*)l, 16, 0, 0);
}

// fast gelu: tanh-form = v * sigmoid(2u)
__device__ __forceinline__ float gelu_fast(float v) {
  float u2 = v * (1.5957691216057308f + 0.0713548162726f * v * v);  // 2u
  float t = __expf(u2);
  float r = __fdividef(1.f, t + 1.f);
  return v - v * r;
}

// ---------------- init routing scratch ----------------
__global__ void init_kernel(int* counts, int* fill, int* pair_b) {
  int t = blockIdx.x * 256 + threadIdx.x;
  if (t < NE) { counts[t] = 0; fill[t] = 0; }
  if (t < CAPP) pair_b[t] = 0;   // dummy pairs point at b=0 (computed, never read back)
}

// ------- fp32 -> bf16 transposing convert, 64x64 tiles, 16B stores -----------
__global__ __launch_bounds__(256)
void transpose_bf_kernel(const float* __restrict__ in, __hip_bfloat16* __restrict__ out,
                         int R, int C) {
  __shared__ float tile[64][65];
  size_t base = (size_t)blockIdx.z * R * C;
  int c0 = blockIdx.x * 64, r0 = blockIdx.y * 64;
  int tr = threadIdx.x >> 4;        // 0..15
  int tc4 = threadIdx.x & 15;       // float4 column
#pragma unroll
  for (int i = 0; i < 4; ++i) {
    float4 v = *(const float4*)(in + base + (size_t)(r0 + tr + i * 16) * C + c0 + tc4 * 4);
    tile[tr + i * 16][tc4 * 4 + 0] = v.x;
    tile[tr + i * 16][tc4 * 4 + 1] = v.y;
    tile[tr + i * 16][tc4 * 4 + 2] = v.z;
    tile[tr + i * 16][tc4 * 4 + 3] = v.w;
  }
  __syncthreads();
  int r8 = threadIdx.x & 7;         // 8-col chunk along output row dir
  int cci = threadIdx.x >> 3;       // 0..31 output rows (columns of tile)
#pragma unroll
  for (int i = 0; i < 2; ++i) {
    int c = cci + i * 32;
    unsigned short u[8];
#pragma unroll
    for (int j = 0; j < 8; ++j) {
      __hip_bfloat16 h = __float2bfloat16(tile[r8 * 8 + j][c]);
      u[j] = *(unsigned short*)&h;
    }
    *(uint4*)((unsigned short*)out + base + (size_t)(c0 + c) * R + r0 + r8 * 8) = *(uint4*)u;
  }
}

// ------- split fp32 x -> [x_hi | x_lo] bf16, [B][2K], all 4 modalities -------
struct SplitArgs {
  const float* x[4];
  unsigned short* xs[4];
  const float* w[4];
  unsigned short* wt[4];
  int K[4];
};

__global__ __launch_bounds__(256)
void split_x_all_kernel(SplitArgs a) {
  int z = blockIdx.y;
  int Kz = a.K[z];
  int kq = Kz >> 2;
  int idx = blockIdx.x * 256 + threadIdx.x;          // one float4 per thread
  if (idx >= NB * kq) return;
  int b = idx / kq, k4 = idx - b * kq;
  float4 v = ((const float4*)(a.x[z] + (size_t)b * Kz))[k4];
  ushort4 hi, lo;
  float f;
  __hip_bfloat16 h;
  h = __float2bfloat16(v.x); f = __bfloat162float(h); hi.x = *(unsigned short*)&h;
  h = __float2bfloat16(v.x - f); lo.x = *(unsigned short*)&h;
  h = __float2bfloat16(v.y); f = __bfloat162float(h); hi.y = *(unsigned short*)&h;
  h = __float2bfloat16(v.y - f); lo.y = *(unsigned short*)&h;
  h = __float2bfloat16(v.z); f = __bfloat162float(h); hi.z = *(unsigned short*)&h;
  h = __float2bfloat16(v.z - f); lo.z = *(unsigned short*)&h;
  h = __float2bfloat16(v.w); f = __bfloat162float(h); hi.w = *(unsigned short*)&h;
  h = __float2bfloat16(v.w - f); lo.w = *(unsigned short*)&h;
  unsigned short* row = a.xs[z] + (size_t)b * (2 * Kz);
  ((ushort4*)row)[k4] = hi;
  ((ushort4*)(row + Kz))[k4] = lo;
}

// transpose+split Wp [K][D] fp32 -> WT [D][2K] bf16 ([w_hiT | w_loT]), all z --
__global__ __launch_bounds__(256)
void split_w_all_kernel(SplitArgs a) {
  int z = blockIdx.z;
  int Kz = a.K[z];
  int k0 = blockIdx.y * 32;
  if (k0 >= Kz) return;
  __shared__ float tile[32][33];
  int d0 = blockIdx.x * 32;
  int tx = threadIdx.x & 31, ty = threadIdx.x >> 5;   // 32x8
  const float* w = a.w[z];
#pragma unroll
  for (int i = 0; i < 32; i += 8)
    tile[ty + i][tx] = w[(size_t)(k0 + ty + i) * DM + d0 + tx];
  __syncthreads();
#pragma unroll
  for (int i = 0; i < 32; i += 8) {
    float v = tile[tx][ty + i];
    __hip_bfloat16 h = __float2bfloat16(v);
    float f = __bfloat162float(h);
    __hip_bfloat16 l = __float2bfloat16(v - f);
    unsigned short* row = a.wt[z] + (size_t)(d0 + ty + i) * (2 * Kz);
    row[k0 + tx] = *(unsigned short*)&h;
    row[Kz + k0 + tx] = *(unsigned short*)&l;
  }
}

// ---------------- shared MFMA inner (proj): 128x128 tile, BK=64, 4 waves -----
__device__ __forceinline__ void mfma_tile(const unsigned short* As, const unsigned short* Bs,
                                          int lane, int wm, int wn, f32x4 acc[4][4]) {
#pragma unroll
  for (int kk = 0; kk < 2; ++kk) {
    bf16x8 af[4], bfr[4];
#pragma unroll
    for (int mi = 0; mi < 4; ++mi) {
      int row = wm * 64 + mi * 16 + (lane & 15);
      int c = (kk * 4 + (lane >> 4)) ^ (row & 7);    // XOR chunk swizzle (read side)
      af[mi] = *(const bf16x8*)((const char*)As + row * 128 + c * 16);
    }
#pragma unroll
    for (int ni = 0; ni < 4; ++ni) {
      int row = wn * 64 + ni * 16 + (lane & 15);
      int c = (kk * 4 + (lane >> 4)) ^ (row & 7);
      bfr[ni] = *(const bf16x8*)((const char*)Bs + row * 128 + c * 16);
    }
#pragma unroll
    for (int mi = 0; mi < 4; ++mi)
#pragma unroll
      for (int ni = 0; ni < 4; ++ni)
        acc[mi][ni] = __builtin_amdgcn_mfma_f32_16x16x32_bf16(af[mi], bfr[ni], acc[mi][ni], 0, 0, 0);
  }
}

// ------- MFMA projections: tokens[b][z][:] = (x_hi+x_lo)@(w_hi+w_lo) + bp ----
struct ProjMArgs {
  const unsigned short* xs[4];   // [B][2K] bf16
  const unsigned short* wt[4];   // [D][2K] bf16
  const float* bp[4];
  int K[4];
};

__global__ __launch_bounds__(256, 4)
void proj_mfma_kernel(ProjMArgs a, float* __restrict__ tokens) {
  int orig = blockIdx.y * 8 + blockIdx.x;
  int swz = (orig & 7) * 64 + (orig >> 3);
  int n0 = (swz & 7) * 128;
  int rest = swz >> 3;
  int z = rest >> 4;
  int m0 = (rest & 15) * 128;
  int Kz = a.K[z];
  const char* Abase0 = (const char*)a.xs[z];
  const char* Bbase0 = (const char*)a.wt[z];
  size_t rowb = (size_t)Kz * 4;
  __shared__ unsigned short As[128 * 64];
  __shared__ unsigned short Bs[128 * 64];
  int t = threadIdx.x, wid = t >> 6, lane = t & 63;
  int wm = wid >> 1, wn = wid & 1;
  int srow = wid * 8 + (lane >> 3);
  int schunk = lane & 7;
  int cc = (schunk ^ (srow & 7)) * 16;
  const char* Abase = Abase0 + (size_t)(m0 + srow) * rowb + cc;
  const char* Bbase = Bbase0 + (size_t)(n0 + srow) * rowb + cc;
  f32x4 acc[4][4] = {};

  for (int s = 0; s < 3; ++s) {
    int ab = ((s == 1) ? Kz : 0) * 2;
    int bb = ((s == 2) ? Kz : 0) * 2;
    int nkt = Kz >> 6;
    for (int kt = 0; kt < nkt; ++kt) {
      int k0b = kt * 128;
#pragma unroll
      for (int q = 0; q < 4; ++q) {
        gload16(Abase + q * 32 * rowb + ab + k0b, (char*)As + (q * 4 + wid) * 1024);
        gload16(Bbase + q * 32 * rowb + bb + k0b, (char*)Bs + (q * 4 + wid) * 1024);
      }
      __syncthreads();
      mfma_tile(As, Bs, lane, wm, wn, acc);
      __syncthreads();
    }
  }
  const float* bp = a.bp[z];
#pragma unroll
  for (int ni = 0; ni < 4; ++ni) {
    int n = n0 + wn * 64 + ni * 16 + (lane & 15);
    float bias = bp[n];
#pragma unroll
    for (int mi = 0; mi < 4; ++mi) {
#pragma unroll
      for (int r = 0; r < 4; ++r) {
        int m = m0 + wm * 64 + mi * 16 + (lane >> 4) * 4 + r;
        tokens[((size_t)m * NM + z) * DM + n] = acc[mi][ni][r] + bias;
      }
    }
  }
}

// -------- fused LayerNorm + router + top-2 gates (one block per token) -------
__global__ __launch_bounds__(256)
void ln_router_kernel(const float* __restrict__ tokens, __hip_bfloat16* __restrict__ tokbf,
                      const float* __restrict__ gam, const float* __restrict__ bet,
                      const float* __restrict__ Wg, const float* __restrict__ bg,
                      float* __restrict__ gates, int* __restrict__ top2i,
                      float* __restrict__ top2w, int* __restrict__ counts) {
  int b = blockIdx.x;
  int t = threadIdx.x, m = t >> 6, lane = t & 63;
  const float* row = tokens + ((size_t)b * NM + m) * DM;
  float4 v[4];
#pragma unroll
  for (int i = 0; i < 4; ++i) v[i] = ((const float4*)row)[lane + i * 64];
  float s = 0.f;
#pragma unroll
  for (int i = 0; i < 4; ++i) s += v[i].x + v[i].y + v[i].z + v[i].w;
#pragma unroll
  for (int off = 32; off > 0; off >>= 1) s += __shfl_xor(s, off);
  float mean = s * (1.f / 1024.f);
  float qv = 0.f;
#pragma unroll
  for (int i = 0; i < 4; ++i) {
    v[i].x -= mean; v[i].y -= mean; v[i].z -= mean; v[i].w -= mean;
    qv += v[i].x * v[i].x + v[i].y * v[i].y + v[i].z * v[i].z + v[i].w * v[i].w;
  }
#pragma unroll
  for (int off = 32; off > 0; off >>= 1) qv += __shfl_xor(qv, off);
  float inv = rsqrtf(qv * (1.f / 1024.f) + 1e-5f);
  float acc[8] = {0, 0, 0, 0, 0, 0, 0, 0};
  __hip_bfloat16* ob = tokbf + ((size_t)b * NM + m) * DM;
#pragma unroll
  for (int i = 0; i < 4; ++i) {
    int j4 = lane + i * 64;
    float4 g = ((const float4*)gam)[j4], bb = ((const float4*)bet)[j4];
    float o[4];
    o[0] = v[i].x * inv * g.x + bb.x;
    o[1] = v[i].y * inv * g.y + bb.y;
    o[2] = v[i].z * inv * g.z + bb.z;
    o[3] = v[i].w * inv * g.w + bb.w;
    ushort4 u;
    __hip_bfloat16 h;
    h = __float2bfloat16(o[0]); u.x = *(unsigned short*)&h;
    h = __float2bfloat16(o[1]); u.y = *(unsigned short*)&h;
    h = __float2bfloat16(o[2]); u.z = *(unsigned short*)&h;
    h = __float2bfloat16(o[3]); u.w = *(unsigned short*)&h;
    ((ushort4*)ob)[j4] = u;
    const float* w = Wg + ((size_t)(m * 1024 + j4 * 4)) * 8;
#pragma unroll
    for (int c = 0; c < 4; ++c) {
      float4 w0 = ((const float4*)(w + c * 8))[0];
      float4 w1 = ((const float4*)(w + c * 8))[1];
      acc[0] += o[c] * w0.x; acc[1] += o[c] * w0.y;
      acc[2] += o[c] * w0.z; acc[3] += o[c] * w0.w;
      acc[4] += o[c] * w1.x; acc[5] += o[c] * w1.y;
      acc[6] += o[c] * w1.z; acc[7] += o[c] * w1.w;
    }
  }
#pragma unroll
  for (int off = 32; off > 0; off >>= 1)
#pragma unroll
    for (int e = 0; e < 8; ++e) acc[e] += __shfl_xor(acc[e], off);
  __shared__ float part[4][8];
  if (lane == 0) {
#pragma unroll
    for (int e = 0; e < 8; ++e) part[m][e] = acc[e];
  }
  __syncthreads();
  if (t == 0) {
    float l[8];
#pragma unroll
    for (int e = 0; e < 8; ++e) l[e] = part[0][e] + part[1][e] + part[2][e] + part[3][e] + bg[e];
    int i0 = 0; float v0 = l[0];
#pragma unroll
    for (int e = 1; e < 8; ++e) if (l[e] > v0) { v0 = l[e]; i0 = e; }
    int i1 = -1; float v1 = -1e30f;
#pragma unroll
    for (int e = 0; e < 8; ++e) if (e != i0 && l[e] > v1) { v1 = l[e]; i1 = e; }
    float ex = __expf(v1 - v0);
    float invd = 1.f / (1.f + ex);
    float w0 = invd, w1 = ex * invd;
#pragma unroll
    for (int e = 0; e < 8; ++e) gates[b * 8 + e] = 0.f;
    gates[b * 8 + i0] = w0;
    gates[b * 8 + i1] = w1;
    top2i[b * 2] = i0; top2i[b * 2 + 1] = i1;
    top2w[b * 2] = w0; top2w[b * 2 + 1] = w1;
    atomicAdd(&counts[i0], 1);
    atomicAdd(&counts[i1], 1);
  }
}

// ---------------- per-expert padded offsets + tile->expert map ---------------
__global__ void offsets_kernel(const int* __restrict__ counts, int* __restrict__ offs,
                               int* __restrict__ tile_e) {
  __shared__ int loc[9];
  int t = threadIdx.x;
  if (t == 0) {
    int o = 0;
    for (int e = 0; e < 8; ++e) { loc[e] = o; o += ((counts[e] + 31) >> 5) << 5; }
    loc[8] = o;
    for (int e = 0; e < 9; ++e) offs[e] = loc[e];
  }
  __syncthreads();
  if (t < NTIL) {
    int ntl = loc[8] >> 5;
    int ex = -1;
    if (t < ntl) {
      int pp = t * 32;
      for (int e = 7; e >= 0; --e) if (pp >= loc[e]) { ex = e; break; }
    }
    tile_e[t] = ex;
  }
}

__global__ void fill_kernel(const int* __restrict__ top2i, int* __restrict__ fill,
                            const int* __restrict__ offs, int* __restrict__ pair_b,
                            int* __restrict__ slots) {
  int b = blockIdx.x * blockDim.x + threadIdx.x;
  if (b >= NB) return;
  for (int k = 0; k < 2; ++k) {
    int e = top2i[b * 2 + k];
    int pos = atomicAdd(&fill[e], 1);
    int s = offs[e] + pos;
    pair_b[s] = b;
    slots[b * 2 + k] = s;
  }
}

// ==== grouped GEMMs: 128x128 tile, BK=32, LDS double-buffer, ONE barrier ====
// ==== per K-step (m248 "minimum 2-phase"): stage(t+1) in flight during   ====
// ==== ds_read+MFMA of t; vmcnt(0)+s_barrier at iteration end only.       ====

// ---------------- grouped GEMM1: gathered tokens @ W1[e] -> gelu -> h (bf16) -
__global__ __launch_bounds__(256, 4)
void gemm1_kernel(const __hip_bfloat16* __restrict__ tokbf,
                  const __hip_bfloat16* __restrict__ W1T,   // [E][H][D]
                  const float* __restrict__ b1,             // [E][H]
                  const int* __restrict__ pair_b,
                  const int* __restrict__ tile_e,
                  __hip_bfloat16* __restrict__ h) {         // [CAPP*4][H]
  // XCD-aware bijective swizzle (nwg=4352, %8==0); n fast within chunk
  int orig = blockIdx.y * 32 + blockIdx.x;
  int swz = (orig & 7) * (4352 / 8) + (orig >> 3);
  int tm = swz >> 5;
  int n0 = (swz & 31) * 128;
  int e = tile_e[tm];
  if (e < 0) return;
  __shared__ unsigned short As[2][4096];   // 2 x (128 rows x 32 bf16, 64B rows)
  __shared__ unsigned short Bs[2][4096];
  int t = threadIdx.x, wid = t >> 6, lane = t & 63;
  int wm = wid >> 1, wn = wid & 1;
  int chunk = t & 3;
  size_t aoff[2], boff[2];
#pragma unroll
  for (int q = 0; q < 2; ++q) {
    int lrow = (t >> 2) + q * 64;
    int cs = (chunk ^ ((lrow >> 1) & 3)) * 16;   // inverse swizzle on global source
    int pb = pair_b[tm * 32 + (lrow >> 2)];
    aoff[q] = (size_t)(pb * 4 + (lrow & 3)) * 2048 + cs;
    boff[q] = (size_t)(n0 + lrow) * 2048 + cs;
  }
  const char* Ab = (const char*)tokbf;
  const char* Bb = (const char*)(W1T + (size_t)e * NH * DM);
  int ldst = wid * 1024;
  int aro[4], bro[4];
#pragma unroll
  for (int i = 0; i < 4; ++i) {
    int row = wm * 64 + i * 16 + (lane & 15);
    aro[i] = row * 64 + (((lane >> 4) ^ ((row >> 1) & 3)) << 4);
    row = wn * 64 + i * 16 + (lane & 15);
    bro[i] = row * 64 + (((lane >> 4) ^ ((row >> 1) & 3)) << 4);
  }
  f32x4 acc[4][4] = {};

  auto stage = [&](int kt, int p) {
    int k0b = kt * 64;
    char* dA = (char*)As[p];
    char* dB = (char*)Bs[p];
#pragma unroll
    for (int q = 0; q < 2; ++q) {
      gload16(Ab + aoff[q] + k0b, dA + q * 4096 + ldst);
      gload16(Bb + boff[q] + k0b, dB + q * 4096 + ldst);
    }
  };
  stage(0, 0);
  asm volatile("s_waitcnt vmcnt(0)" ::: "memory");
  __builtin_amdgcn_s_barrier();
  __builtin_amdgcn_sched_barrier(0);
  const int NT = 32;                       // K = 1024 / 32
  int cur = 0;
  for (int kt = 0; kt < NT; ++kt) {
    if (kt < NT - 1) stage(kt + 1, cur ^ 1);   // next tile in flight during compute
    const char* a0 = (const char*)As[cur];
    const char* b0 = (const char*)Bs[cur];
    bf16x8 af[4], bfv[4];
#pragma unroll
    for (int i = 0; i < 4; ++i) af[i] = *(const bf16x8*)(a0 + aro[i]);
#pragma unroll
    for (int i = 0; i < 4; ++i) bfv[i] = *(const bf16x8*)(b0 + bro[i]);
    __builtin_amdgcn_s_setprio(1);
#pragma unroll
    for (int mi = 0; mi < 4; ++mi)
#pragma unroll
      for (int ni = 0; ni < 4; ++ni)
        acc[mi][ni] = __builtin_amdgcn_mfma_f32_16x16x32_bf16(af[mi], bfv[ni], acc[mi][ni], 0, 0, 0);
    __builtin_amdgcn_s_setprio(0);
    if (kt < NT - 1) {
      asm volatile("s_waitcnt vmcnt(0)" ::: "memory");   // next tile resident
      __builtin_amdgcn_s_barrier();                      // all reads of cur retired
      __builtin_amdgcn_sched_barrier(0);
      cur ^= 1;
    }
  }
  int rbase = tm * 128 + wm * 64;
#pragma unroll
  for (int ni = 0; ni < 4; ++ni) {
    int col = n0 + wn * 64 + ni * 16 + (lane & 15);
    float bias = b1[e * NH + col];
#pragma unroll
    for (int mi = 0; mi < 4; ++mi) {
#pragma unroll
      for (int r = 0; r < 4; ++r) {
        int row = rbase + mi * 16 + (lane >> 4) * 4 + r;
        float v = acc[mi][ni][r] + bias;
        h[(size_t)row * NH + col] = __float2bfloat16(gelu_fast(v));
      }
    }
  }
}

// ---------------- grouped GEMM2: h @ W2[e] + b2 -> eo (fp32) -----------------
__global__ __launch_bounds__(256, 4)
void gemm2_kernel(const __hip_bfloat16* __restrict__ h,
                  const __hip_bfloat16* __restrict__ W2T,   // [E][D][H]
                  const float* __restrict__ b2,             // [E][D]
                  const int* __restrict__ tile_e,
                  float* __restrict__ eo) {                 // [CAPP*4][D]
  // XCD-aware bijective swizzle (nwg=1088, %8==0)
  int orig = blockIdx.y * 8 + blockIdx.x;
  int swz = (orig & 7) * (1088 / 8) + (orig >> 3);
  int tm = swz >> 3;
  int n0 = (swz & 7) * 128;
  int e = tile_e[tm];
  if (e < 0) return;
  __shared__ unsigned short As[2][4096];
  __shared__ unsigned short Bs[2][4096];
  int t = threadIdx.x, wid = t >> 6, lane = t & 63;
  int wm = wid >> 1, wn = wid & 1;
  int chunk = t & 3;
  size_t aoff[2], boff[2];
#pragma unroll
  for (int q = 0; q < 2; ++q) {
    int lrow = (t >> 2) + q * 64;
    int cs = (chunk ^ ((lrow >> 1) & 3)) * 16;
    aoff[q] = (size_t)(tm * 128 + lrow) * 8192 + cs;
    boff[q] = (size_t)(n0 + lrow) * 8192 + cs;
  }
  const char* Ab = (const char*)h;
  const char* Bb = (const char*)(W2T + (size_t)e * DM * NH);
  int ldst = wid * 1024;
  int aro[4], bro[4];
#pragma unroll
  for (int i = 0; i < 4; ++i) {
    int row = wm * 64 + i * 16 + (lane & 15);
    aro[i] = row * 64 + (((lane >> 4) ^ ((row >> 1) & 3)) << 4);
    row = wn * 64 + i * 16 + (lane & 15);
    bro[i] = row * 64 + (((lane >> 4) ^ ((row >> 1) & 3)) << 4);
  }
  f32x4 acc[4][4] = {};

  auto stage = [&](int kt, int p) {
    int k0b = kt * 64;
    char* dA = (char*)As[p];
    char* dB = (char*)Bs[p];
#pragma unroll
    for (int q = 0; q < 2; ++q) {
      gload16(Ab + aoff[q] + k0b, dA + q * 4096 + ldst);
      gload16(Bb + boff[q] + k0b, dB + q * 4096 + ldst);
    }
  };
  stage(0, 0);
  asm volatile("s_waitcnt vmcnt(0)" ::: "memory");
  __builtin_amdgcn_s_barrier();
  __builtin_amdgcn_sched_barrier(0);
  const int NT = 128;                      // K = 4096 / 32
  int cur = 0;
  for (int kt = 0; kt < NT; ++kt) {
    if (kt < NT - 1) stage(kt + 1, cur ^ 1);
    const char* a0 = (const char*)As[cur];
    const char* b0 = (const char*)Bs[cur];
    bf16x8 af[4], bfv[4];
#pragma unroll
    for (int i = 0; i < 4; ++i) af[i] = *(const bf16x8*)(a0 + aro[i]);
#pragma unroll
    for (int i = 0; i < 4; ++i) bfv[i] = *(const bf16x8*)(b0 + bro[i]);
    __builtin_amdgcn_s_setprio(1);
#pragma unroll
    for (int mi = 0; mi < 4; ++mi)
#pragma unroll
      for (int ni = 0; ni < 4; ++ni)
        acc[mi][ni] = __builtin_amdgcn_mfma_f32_16x16x32_bf16(af[mi], bfv[ni], acc[mi][ni], 0, 0, 0);
    __builtin_amdgcn_s_setprio(0);
    if (kt < NT - 1) {
      asm volatile("s_waitcnt vmcnt(0)" ::: "memory");
      __builtin_amdgcn_s_barrier();
      __builtin_amdgcn_sched_barrier(0);
      cur ^= 1;
    }
  }
  int rbase = tm * 128 + wm * 64;
#pragma unroll
  for (int ni = 0; ni < 4; ++ni) {
    int col = n0 + wn * 64 + ni * 16 + (lane & 15);
    float bias = b2[e * DM + col];
#pragma unroll
    for (int mi = 0; mi < 4; ++mi) {
#pragma unroll
      for (int r = 0; r < 4; ++r) {
        int row = rbase + mi * 16 + (lane >> 4) * 4 + r;
        eo[(size_t)row * DM + col] = acc[mi][ni][r] + bias;
      }
    }
  }
}

// ---------------- combine: gate-weighted sum + pooled mean -------------------
__global__ __launch_bounds__(256)
void combine_kernel(const float* __restrict__ eo, const int* __restrict__ slots,
                    const float* __restrict__ top2w, float* __restrict__ pooled,
                    float* __restrict__ combined) {
  int b = blockIdx.x, t = threadIdx.x;
  int s0 = slots[b * 2], s1 = slots[b * 2 + 1];
  float w0 = top2w[b * 2], w1 = top2w[b * 2 + 1];
  float px = 0, py = 0, pz = 0, pw = 0;
#pragma unroll
  for (int m = 0; m < 4; ++m) {
    float4 a = ((const float4*)(eo + (size_t)(s0 * 4 + m) * DM))[t];
    float4 c = ((const float4*)(eo + (size_t)(s1 * 4 + m) * DM))[t];
    float4 v;
    v.x = w0 * a.x + w1 * c.x;
    v.y = w0 * a.y + w1 * c.y;
    v.z = w0 * a.z + w1 * c.z;
    v.w = w0 * a.w + w1 * c.w;
    ((float4*)(combined + ((size_t)b * NM + m) * DM))[t] = v;
    px += v.x; py += v.y; pz += v.z; pw += v.w;
  }
  float4 pv; pv.x = px * 0.25f; pv.y = py * 0.25f; pv.z = pz * 0.25f; pv.w = pw * 0.25f;
  ((float4*)(pooled + (size_t)b * DM))[t] = pv;
}

// ---------------- balance loss ----------------------------------------------
__global__ __launch_bounds__(256)
void balance_kernel(const float* __restrict__ gates, const int* __restrict__ counts,
                    float* __restrict__ out_bal) {
  int t = threadIdx.x;
  float imp[8] = {0, 0, 0, 0, 0, 0, 0, 0};
  for (int b = t; b < NB; b += 256) {
#pragma unroll
    for (int e = 0; e < 8; ++e) imp[e] += gates[b * 8 + e];
  }
  __shared__ float red[256];
  __shared__ float impE[8];
  for (int e = 0; e < 8; ++e) {
    red[t] = imp[e];
    __syncthreads();
    for (int s = 128; s > 0; s >>= 1) { if (t < s) red[t] += red[t + s]; __syncthreads(); }
    if (t == 0) impE[e] = red[0];
    __syncthreads();
  }
  if (t == 0) {
    float mi = 0, ml = 0;
    for (int e = 0; e < 8; ++e) { mi += impE[e]; ml += (float)counts[e]; }
    mi *= 0.125f; ml *= 0.125f;
    float vi = 0, vl = 0;
    for (int e = 0; e < 8; ++e) {
      float di = impE[e] - mi, dl = (float)counts[e] - ml;
      vi += di * di; vl += dl * dl;
    }
    vi *= (1.f / 7.f); vl *= (1.f / 7.f);           // ddof=1
    float cvi = vi / (mi * mi + 1e-10f);
    float cvl = vl / (ml * ml + 1e-10f);
    out_bal[0] = 0.01f * (cvi + cvl);
  }
}

// ---------------- host launch ------------------------------------------------
extern "C" void kernel_launch(void* const* d_in, const int* in_sizes, int n_in,
                              void* d_out, int out_size, void* d_ws, size_t ws_size,
                              hipStream_t stream) {
  (void)in_sizes; (void)n_in; (void)out_size; (void)ws_size;
  const float* xin[4] = {(const float*)d_in[0], (const float*)d_in[3],
                         (const float*)d_in[6], (const float*)d_in[9]};
  const float* win[4] = {(const float*)d_in[1], (const float*)d_in[4],
                         (const float*)d_in[7], (const float*)d_in[10]};
  const float* bpin[4] = {(const float*)d_in[2], (const float*)d_in[5],
                          (const float*)d_in[8], (const float*)d_in[11]};
  const int Ks[4] = {768, 1536, 512, 2048};
  const float* ln_g = (const float*)d_in[12];
  const float* ln_b = (const float*)d_in[13];
  const float* Wg = (const float*)d_in[14];
  const float* bg = (const float*)d_in[15];
  const float* W1 = (const float*)d_in[16];
  const float* b1 = (const float*)d_in[17];
  const float* W2 = (const float*)d_in[18];
  const float* b2 = (const float*)d_in[19];

  char* p = (char*)d_ws;
  auto take = [&](size_t n) { char* r = p; p += (n + 255) & ~(size_t)255; return r; };
  __hip_bfloat16* W1T = (__hip_bfloat16*)take((size_t)NE * NH * DM * 2);
  __hip_bfloat16* W2T = (__hip_bfloat16*)take((size_t)NE * NH * DM * 2);
  float* tokens = (float*)take((size_t)NB * NM * DM * 4);
  __hip_bfloat16* tokbf = (__hip_bfloat16*)take((size_t)NB * NM * DM * 2);
  __hip_bfloat16* hbuf = (__hip_bfloat16*)take((size_t)CAPP * 4 * NH * 2);
  float* eo = (float*)take((size_t)CAPP * 4 * DM * 4);
  int* top2i = (int*)take(NB * 2 * 4);
  float* top2w = (float*)take(NB * 2 * 4);
  int* slots = (int*)take(NB * 2 * 4);
  int* pair_b = (int*)take(CAPP * 4);
  int* tile_e = (int*)take(NTIL * 4);
  int* counts = (int*)take(64);
  int* fill = (int*)take(64);
  int* offs = (int*)take(64);

  // XS/WT alias hbuf (dead until gemm1, which runs after proj_mfma)
  unsigned short* scratch = (unsigned short*)hbuf;
  ProjMArgs pm;
  SplitArgs sa;
  {
    unsigned short* q = scratch;
    for (int z = 0; z < 4; ++z) { pm.xs[z] = q; sa.xs[z] = q; q += (size_t)NB * 2 * Ks[z]; }
    for (int z = 0; z < 4; ++z) { pm.wt[z] = q; sa.wt[z] = q; q += (size_t)DM * 2 * Ks[z]; }
    for (int z = 0; z < 4; ++z) {
      pm.bp[z] = bpin[z]; pm.K[z] = Ks[z];
      sa.x[z] = xin[z]; sa.w[z] = win[z]; sa.K[z] = Ks[z];
    }
  }

  float* out = (float*)d_out;
  float* out_pooled = out;                    // [2048][1024]
  float* out_combined = out + 2097152;        // [2048][4][1024]
  float* out_gates = out + 10485760;          // [2048][8]
  float* out_bal = out + 10502144;            // scalar

  init_kernel<<<dim3(17), dim3(256), 0, stream>>>(counts, fill, pair_b);
  split_x_all_kernel<<<dim3(4096, 4), dim3(256), 0, stream>>>(sa);
  split_w_all_kernel<<<dim3(32, 64, 4), dim3(256), 0, stream>>>(sa);
  transpose_bf_kernel<<<dim3(64, 16, 8), dim3(256), 0, stream>>>(W1, W1T, 1024, 4096);
  transpose_bf_kernel<<<dim3(16, 64, 8), dim3(256), 0, stream>>>(W2, W2T, 4096, 1024);
  proj_mfma_kernel<<<dim3(8, 64), dim3(256), 0, stream>>>(pm, tokens);
  ln_router_kernel<<<dim3(NB), dim3(256), 0, stream>>>(tokens, tokbf, ln_g, ln_b, Wg, bg,
                                                       out_gates, top2i, top2w, counts);
  offsets_kernel<<<dim3(1), dim3(256), 0, stream>>>(counts, offs, tile_e);
  fill_kernel<<<dim3(8), dim3(256), 0, stream>>>(top2i, fill, offs, pair_b, slots);
  gemm1_kernel<<<dim3(32, NTIL), dim3(256), 0, stream>>>(tokbf, W1T, b1, pair_b, tile_e, hbuf);
  gemm2_kernel<<<dim3(8, NTIL), dim3(256), 0, stream>>>(hbuf, W2T, b2, tile_e, eo);
  combine_kernel<<<dim3(NB), dim3(256), 0, stream>>>(eo, slots, top2w, out_pooled, out_combined);
  balance_kernel<<<dim3(1), dim3(256), 0, stream>>>(out_gates, counts, out_bal);
}

// Round 11
// 720.301 us; speedup vs baseline: 1.0849x; 1.0849x over previous
//
#include <hip/hip_runtime.h>
#include <hip/hip_bf16.h>
#include <cstdint>
#include <cstddef>

// Problem constants
#define NB 2048      // batch tokens
#define NM 4         // modalities
#define DM 1024      // model dim
#define NE 8         // experts
#define NH 4096      // expert hidden
#define CAPP 4352    // padded (b,expert)-pair capacity: 4096 + 8*32
#define NTIL 136     // CAPP/32 pair-tiles (128 gathered rows each)

typedef __attribute__((ext_vector_type(8))) short bf16x8;
typedef __attribute__((ext_vector_type(4))) float f32x4;

__device__ __forceinline__ void gload16(const void* g, void* l) {
  // async global->LDS, 16B/lane; LDS dest = wave-uniform base + lane*16
  __builtin_amdgcn_global_load_lds((const __attribute__((address_space(1))) void*)g,
                                   (__attribute__((address_space(3))) void*)l, 16, 0, 0);
}

// fast gelu: tanh-form = v * sigmoid(2u)
__device__ __forceinline__ float gelu_fast(float v) {
  float u2 = v * (1.5957691216057308f + 0.0713548162726f * v * v);  // 2u
  float t = __expf(u2);
  float r = __fdividef(1.f, t + 1.f);
  return v - v * r;
}

// ---------------- init routing scratch ----------------
__global__ void init_kernel(int* counts, int* fill, int* pair_b) {
  int t = blockIdx.x * 256 + threadIdx.x;
  if (t < NE) { counts[t] = 0; fill[t] = 0; }
  if (t < CAPP) pair_b[t] = 0;   // dummy pairs point at b=0 (computed, never read back)
}

// ------- fp32 -> bf16 transposing convert, 64x64 tiles, 16B stores -----------
__global__ __launch_bounds__(256)
void transpose_bf_kernel(const float* __restrict__ in, __hip_bfloat16* __restrict__ out,
                         int R, int C) {
  __shared__ float tile[64][65];
  size_t base = (size_t)blockIdx.z * R * C;
  int c0 = blockIdx.x * 64, r0 = blockIdx.y * 64;
  int tr = threadIdx.x >> 4;        // 0..15
  int tc4 = threadIdx.x & 15;       // float4 column
#pragma unroll
  for (int i = 0; i < 4; ++i) {
    float4 v = *(const float4*)(in + base + (size_t)(r0 + tr + i * 16) * C + c0 + tc4 * 4);
    tile[tr + i * 16][tc4 * 4 + 0] = v.x;
    tile[tr + i * 16][tc4 * 4 + 1] = v.y;
    tile[tr + i * 16][tc4 * 4 + 2] = v.z;
    tile[tr + i * 16][tc4 * 4 + 3] = v.w;
  }
  __syncthreads();
  int r8 = threadIdx.x & 7;         // 8-col chunk along output row dir
  int cci = threadIdx.x >> 3;       // 0..31 output rows (columns of tile)
#pragma unroll
  for (int i = 0; i < 2; ++i) {
    int c = cci + i * 32;
    unsigned short u[8];
#pragma unroll
    for (int j = 0; j < 8; ++j) {
      __hip_bfloat16 h = __float2bfloat16(tile[r8 * 8 + j][c]);
      u[j] = *(unsigned short*)&h;
    }
    *(uint4*)((unsigned short*)out + base + (size_t)(c0 + c) * R + r0 + r8 * 8) = *(uint4*)u;
  }
}

// ------- split fp32 x -> [x_hi | x_lo] bf16, [B][2K], all 4 modalities -------
struct SplitArgs {
  const float* x[4];
  unsigned short* xs[4];
  const float* w[4];
  unsigned short* wt[4];
  int K[4];
};

__global__ __launch_bounds__(256)
void split_x_all_kernel(SplitArgs a) {
  int z = blockIdx.y;
  int Kz = a.K[z];
  int kq = Kz >> 2;
  int idx = blockIdx.x * 256 + threadIdx.x;          // one float4 per thread
  if (idx >= NB * kq) return;
  int b = idx / kq, k4 = idx - b * kq;
  float4 v = ((const float4*)(a.x[z] + (size_t)b * Kz))[k4];
  ushort4 hi, lo;
  float f;
  __hip_bfloat16 h;
  h = __float2bfloat16(v.x); f = __bfloat162float(h); hi.x = *(unsigned short*)&h;
  h = __float2bfloat16(v.x - f); lo.x = *(unsigned short*)&h;
  h = __float2bfloat16(v.y); f = __bfloat162float(h); hi.y = *(unsigned short*)&h;
  h = __float2bfloat16(v.y - f); lo.y = *(unsigned short*)&h;
  h = __float2bfloat16(v.z); f = __bfloat162float(h); hi.z = *(unsigned short*)&h;
  h = __float2bfloat16(v.z - f); lo.z = *(unsigned short*)&h;
  h = __float2bfloat16(v.w); f = __bfloat162float(h); hi.w = *(unsigned short*)&h;
  h = __float2bfloat16(v.w - f); lo.w = *(unsigned short*)&h;
  unsigned short* row = a.xs[z] + (size_t)b * (2 * Kz);
  ((ushort4*)row)[k4] = hi;
  ((ushort4*)(row + Kz))[k4] = lo;
}

// transpose+split Wp [K][D] fp32 -> WT [D][2K] bf16 ([w_hiT | w_loT]), all z --
__global__ __launch_bounds__(256)
void split_w_all_kernel(SplitArgs a) {
  int z = blockIdx.z;
  int Kz = a.K[z];
  int k0 = blockIdx.y * 32;
  if (k0 >= Kz) return;
  __shared__ float tile[32][33];
  int d0 = blockIdx.x * 32;
  int tx = threadIdx.x & 31, ty = threadIdx.x >> 5;   // 32x8
  const float* w = a.w[z];
#pragma unroll
  for (int i = 0; i < 32; i += 8)
    tile[ty + i][tx] = w[(size_t)(k0 + ty + i) * DM + d0 + tx];
  __syncthreads();
#pragma unroll
  for (int i = 0; i < 32; i += 8) {
    float v = tile[tx][ty + i];
    __hip_bfloat16 h = __float2bfloat16(v);
    float f = __bfloat162float(h);
    __hip_bfloat16 l = __float2bfloat16(v - f);
    unsigned short* row = a.wt[z] + (size_t)(d0 + ty + i) * (2 * Kz);
    row[k0 + tx] = *(unsigned short*)&h;
    row[Kz + k0 + tx] = *(unsigned short*)&l;
  }
}

// ---------------- shared MFMA inner: 128x128 tile, BK=64, 4 waves (2x2) ------
__device__ __forceinline__ void mfma_tile(const unsigned short* As, const unsigned short* Bs,
                                          int lane, int wm, int wn, f32x4 acc[4][4]) {
#pragma unroll
  for (int kk = 0; kk < 2; ++kk) {
    bf16x8 af[4], bfr[4];
#pragma unroll
    for (int mi = 0; mi < 4; ++mi) {
      int row = wm * 64 + mi * 16 + (lane & 15);
      int c = (kk * 4 + (lane >> 4)) ^ (row & 7);    // XOR chunk swizzle (read side)
      af[mi] = *(const bf16x8*)((const char*)As + row * 128 + c * 16);
    }
#pragma unroll
    for (int ni = 0; ni < 4; ++ni) {
      int row = wn * 64 + ni * 16 + (lane & 15);
      int c = (kk * 4 + (lane >> 4)) ^ (row & 7);
      bfr[ni] = *(const bf16x8*)((const char*)Bs + row * 128 + c * 16);
    }
#pragma unroll
    for (int mi = 0; mi < 4; ++mi)
#pragma unroll
      for (int ni = 0; ni < 4; ++ni)
        acc[mi][ni] = __builtin_amdgcn_mfma_f32_16x16x32_bf16(af[mi], bfr[ni], acc[mi][ni], 0, 0, 0);
  }
}

// ------- MFMA projections: tokens[b][z][:] = (x_hi+x_lo)@(w_hi+w_lo) + bp ----
struct ProjMArgs {
  const unsigned short* xs[4];   // [B][2K] bf16
  const unsigned short* wt[4];   // [D][2K] bf16
  const float* bp[4];
  int K[4];
};

__global__ __launch_bounds__(256, 4)
void proj_mfma_kernel(ProjMArgs a, float* __restrict__ tokens) {
  int orig = blockIdx.y * 8 + blockIdx.x;
  int swz = (orig & 7) * 64 + (orig >> 3);
  int n0 = (swz & 7) * 128;
  int rest = swz >> 3;
  int z = rest >> 4;
  int m0 = (rest & 15) * 128;
  int Kz = a.K[z];
  const char* Abase0 = (const char*)a.xs[z];
  const char* Bbase0 = (const char*)a.wt[z];
  size_t rowb = (size_t)Kz * 4;
  __shared__ unsigned short As[128 * 64];
  __shared__ unsigned short Bs[128 * 64];
  int t = threadIdx.x, wid = t >> 6, lane = t & 63;
  int wm = wid >> 1, wn = wid & 1;
  int srow = wid * 8 + (lane >> 3);
  int schunk = lane & 7;
  int cc = (schunk ^ (srow & 7)) * 16;
  const char* Abase = Abase0 + (size_t)(m0 + srow) * rowb + cc;
  const char* Bbase = Bbase0 + (size_t)(n0 + srow) * rowb + cc;
  f32x4 acc[4][4] = {};

  for (int s = 0; s < 3; ++s) {
    int ab = ((s == 1) ? Kz : 0) * 2;
    int bb = ((s == 2) ? Kz : 0) * 2;
    int nkt = Kz >> 6;
    for (int kt = 0; kt < nkt; ++kt) {
      int k0b = kt * 128;
#pragma unroll
      for (int q = 0; q < 4; ++q) {
        gload16(Abase + q * 32 * rowb + ab + k0b, (char*)As + (q * 4 + wid) * 1024);
        gload16(Bbase + q * 32 * rowb + bb + k0b, (char*)Bs + (q * 4 + wid) * 1024);
      }
      __syncthreads();
      mfma_tile(As, Bs, lane, wm, wn, acc);
      __syncthreads();
    }
  }
  const float* bp = a.bp[z];
#pragma unroll
  for (int ni = 0; ni < 4; ++ni) {
    int n = n0 + wn * 64 + ni * 16 + (lane & 15);
    float bias = bp[n];
#pragma unroll
    for (int mi = 0; mi < 4; ++mi) {
#pragma unroll
      for (int r = 0; r < 4; ++r) {
        int m = m0 + wm * 64 + mi * 16 + (lane >> 4) * 4 + r;
        tokens[((size_t)m * NM + z) * DM + n] = acc[mi][ni][r] + bias;
      }
    }
  }
}

// -------- fused LayerNorm + router + top-2 gates (one block per token) -------
__global__ __launch_bounds__(256)
void ln_router_kernel(const float* __restrict__ tokens, __hip_bfloat16* __restrict__ tokbf,
                      const float* __restrict__ gam, const float* __restrict__ bet,
                      const float* __restrict__ Wg, const float* __restrict__ bg,
                      float* __restrict__ gates, int* __restrict__ top2i,
                      float* __restrict__ top2w, int* __restrict__ counts) {
  int b = blockIdx.x;
  int t = threadIdx.x, m = t >> 6, lane = t & 63;
  const float* row = tokens + ((size_t)b * NM + m) * DM;
  float4 v[4];
#pragma unroll
  for (int i = 0; i < 4; ++i) v[i] = ((const float4*)row)[lane + i * 64];
  float s = 0.f;
#pragma unroll
  for (int i = 0; i < 4; ++i) s += v[i].x + v[i].y + v[i].z + v[i].w;
#pragma unroll
  for (int off = 32; off > 0; off >>= 1) s += __shfl_xor(s, off);
  float mean = s * (1.f / 1024.f);
  float qv = 0.f;
#pragma unroll
  for (int i = 0; i < 4; ++i) {
    v[i].x -= mean; v[i].y -= mean; v[i].z -= mean; v[i].w -= mean;
    qv += v[i].x * v[i].x + v[i].y * v[i].y + v[i].z * v[i].z + v[i].w * v[i].w;
  }
#pragma unroll
  for (int off = 32; off > 0; off >>= 1) qv += __shfl_xor(qv, off);
  float inv = rsqrtf(qv * (1.f / 1024.f) + 1e-5f);
  float acc[8] = {0, 0, 0, 0, 0, 0, 0, 0};
  __hip_bfloat16* ob = tokbf + ((size_t)b * NM + m) * DM;
#pragma unroll
  for (int i = 0; i < 4; ++i) {
    int j4 = lane + i * 64;
    float4 g = ((const float4*)gam)[j4], bb = ((const float4*)bet)[j4];
    float o[4];
    o[0] = v[i].x * inv * g.x + bb.x;
    o[1] = v[i].y * inv * g.y + bb.y;
    o[2] = v[i].z * inv * g.z + bb.z;
    o[3] = v[i].w * inv * g.w + bb.w;
    ushort4 u;
    __hip_bfloat16 h;
    h = __float2bfloat16(o[0]); u.x = *(unsigned short*)&h;
    h = __float2bfloat16(o[1]); u.y = *(unsigned short*)&h;
    h = __float2bfloat16(o[2]); u.z = *(unsigned short*)&h;
    h = __float2bfloat16(o[3]); u.w = *(unsigned short*)&h;
    ((ushort4*)ob)[j4] = u;
    const float* w = Wg + ((size_t)(m * 1024 + j4 * 4)) * 8;
#pragma unroll
    for (int c = 0; c < 4; ++c) {
      float4 w0 = ((const float4*)(w + c * 8))[0];
      float4 w1 = ((const float4*)(w + c * 8))[1];
      acc[0] += o[c] * w0.x; acc[1] += o[c] * w0.y;
      acc[2] += o[c] * w0.z; acc[3] += o[c] * w0.w;
      acc[4] += o[c] * w1.x; acc[5] += o[c] * w1.y;
      acc[6] += o[c] * w1.z; acc[7] += o[c] * w1.w;
    }
  }
#pragma unroll
  for (int off = 32; off > 0; off >>= 1)
#pragma unroll
    for (int e = 0; e < 8; ++e) acc[e] += __shfl_xor(acc[e], off);
  __shared__ float part[4][8];
  if (lane == 0) {
#pragma unroll
    for (int e = 0; e < 8; ++e) part[m][e] = acc[e];
  }
  __syncthreads();
  if (t == 0) {
    float l[8];
#pragma unroll
    for (int e = 0; e < 8; ++e) l[e] = part[0][e] + part[1][e] + part[2][e] + part[3][e] + bg[e];
    int i0 = 0; float v0 = l[0];
#pragma unroll
    for (int e = 1; e < 8; ++e) if (l[e] > v0) { v0 = l[e]; i0 = e; }
    int i1 = -1; float v1 = -1e30f;
#pragma unroll
    for (int e = 0; e < 8; ++e) if (e != i0 && l[e] > v1) { v1 = l[e]; i1 = e; }
    float ex = __expf(v1 - v0);
    float invd = 1.f / (1.f + ex);
    float w0 = invd, w1 = ex * invd;
#pragma unroll
    for (int e = 0; e < 8; ++e) gates[b * 8 + e] = 0.f;
    gates[b * 8 + i0] = w0;
    gates[b * 8 + i1] = w1;
    top2i[b * 2] = i0; top2i[b * 2 + 1] = i1;
    top2w[b * 2] = w0; top2w[b * 2 + 1] = w1;
    atomicAdd(&counts[i0], 1);
    atomicAdd(&counts[i1], 1);
  }
}

// ---------------- per-expert padded offsets + tile->expert map ---------------
__global__ void offsets_kernel(const int* __restrict__ counts, int* __restrict__ offs,
                               int* __restrict__ tile_e) {
  __shared__ int loc[9];
  int t = threadIdx.x;
  if (t == 0) {
    int o = 0;
    for (int e = 0; e < 8; ++e) { loc[e] = o; o += ((counts[e] + 31) >> 5) << 5; }
    loc[8] = o;
    for (int e = 0; e < 9; ++e) offs[e] = loc[e];
  }
  __syncthreads();
  if (t < NTIL) {
    int ntl = loc[8] >> 5;
    int ex = -1;
    if (t < ntl) {
      int pp = t * 32;
      for (int e = 7; e >= 0; --e) if (pp >= loc[e]) { ex = e; break; }
    }
    tile_e[t] = ex;
  }
}

__global__ void fill_kernel(const int* __restrict__ top2i, int* __restrict__ fill,
                            const int* __restrict__ offs, int* __restrict__ pair_b,
                            int* __restrict__ slots) {
  int b = blockIdx.x * blockDim.x + threadIdx.x;
  if (b >= NB) return;
  for (int k = 0; k < 2; ++k) {
    int e = top2i[b * 2 + k];
    int pos = atomicAdd(&fill[e], 1);
    int s = offs[e] + pos;
    pair_b[s] = b;
    slots[b * 2 + k] = s;
  }
}

// ---------------- grouped GEMM1: gathered tokens @ W1[e] -> gelu -> h (bf16) -
__global__ __launch_bounds__(256, 4)
void gemm1_kernel(const __hip_bfloat16* __restrict__ tokbf,
                  const __hip_bfloat16* __restrict__ W1T,   // [E][H][D]
                  const float* __restrict__ b1,             // [E][H]
                  const int* __restrict__ pair_b,
                  const int* __restrict__ tile_e,
                  __hip_bfloat16* __restrict__ h) {         // [CAPP*4][H]
  // XCD-aware bijective swizzle (nwg=4352, %8==0); n fast within chunk
  int orig = blockIdx.y * 32 + blockIdx.x;
  int swz = (orig & 7) * (4352 / 8) + (orig >> 3);
  int tm = swz >> 5;
  int n0 = (swz & 31) * 128;
  int e = tile_e[tm];
  if (e < 0) return;
  __shared__ unsigned short As[128 * 64];
  __shared__ unsigned short Bs[128 * 64];
  int t = threadIdx.x, wid = t >> 6, lane = t & 63;
  int wm = wid >> 1, wn = wid & 1;
  int srow = wid * 8 + (lane >> 3);   // staging row for q=0 (+32 per q)
  int schunk = lane & 7;
  int cc = (schunk ^ (srow & 7)) * 16;   // loop-invariant swizzled chunk
  unsigned ro[4];
#pragma unroll
  for (int q = 0; q < 4; ++q) {
    int pb = pair_b[tm * 32 + (srow >> 2) + q * 8];
    ro[q] = (unsigned)(pb * NM + (srow & 3)) * (DM * 2);
  }
  const char* Abase = (const char*)tokbf + cc;
  const char* Bbase = (const char*)(W1T + (size_t)e * NH * DM)
                      + (size_t)(n0 + srow) * (DM * 2) + cc;
  f32x4 acc[4][4] = {};

  for (int kt = 0; kt < 16; ++kt) {   // K = 1024 bf16 = 2048B, 128B per step
    int k0b = kt * 128;
#pragma unroll
    for (int q = 0; q < 4; ++q) {
      gload16(Abase + ro[q] + k0b, (char*)As + (q * 4 + wid) * 1024);
      gload16(Bbase + q * (32 * DM * 2) + k0b, (char*)Bs + (q * 4 + wid) * 1024);
    }
    __syncthreads();
    mfma_tile(As, Bs, lane, wm, wn, acc);
    __syncthreads();
  }
  int rbase = tm * 128 + wm * 64;
#pragma unroll
  for (int ni = 0; ni < 4; ++ni) {
    int col = n0 + wn * 64 + ni * 16 + (lane & 15);
    float bias = b1[e * NH + col];
#pragma unroll
    for (int mi = 0; mi < 4; ++mi) {
#pragma unroll
      for (int r = 0; r < 4; ++r) {
        int row = rbase + mi * 16 + (lane >> 4) * 4 + r;
        float v = acc[mi][ni][r] + bias;
        h[(size_t)row * NH + col] = __float2bfloat16(gelu_fast(v));
      }
    }
  }
}

// ---------------- grouped GEMM2: h @ W2[e] + b2 -> eo (fp32) -----------------
__global__ __launch_bounds__(256, 4)
void gemm2_kernel(const __hip_bfloat16* __restrict__ h,
                  const __hip_bfloat16* __restrict__ W2T,   // [E][D][H]
                  const float* __restrict__ b2,             // [E][D]
                  const int* __restrict__ tile_e,
                  float* __restrict__ eo) {                 // [CAPP*4][D]
  // XCD-aware bijective swizzle (nwg=1088, %8==0)
  int orig = blockIdx.y * 8 + blockIdx.x;
  int swz = (orig & 7) * (1088 / 8) + (orig >> 3);
  int tm = swz >> 3;
  int n0 = (swz & 7) * 128;
  int e = tile_e[tm];
  if (e < 0) return;
  __shared__ unsigned short As[128 * 64];
  __shared__ unsigned short Bs[128 * 64];
  int t = threadIdx.x, wid = t >> 6, lane = t & 63;
  int wm = wid >> 1, wn = wid & 1;
  int srow = wid * 8 + (lane >> 3);
  int schunk = lane & 7;
  int cc = (schunk ^ (srow & 7)) * 16;
  const char* Abase = (const char*)h + (size_t)(tm * 128 + srow) * (NH * 2) + cc;
  const char* Bbase = (const char*)(W2T + (size_t)e * DM * NH)
                      + (size_t)(n0 + srow) * (NH * 2) + cc;
  f32x4 acc[4][4] = {};

  for (int kt = 0; kt < 64; ++kt) {   // K = 4096 bf16 = 8192B
    int k0b = kt * 128;
#pragma unroll
    for (int q = 0; q < 4; ++q) {
      gload16(Abase + (size_t)q * (32 * NH * 2) + k0b, (char*)As + (q * 4 + wid) * 1024);
      gload16(Bbase + (size_t)q * (32 * NH * 2) + k0b, (char*)Bs + (q * 4 + wid) * 1024);
    }
    __syncthreads();
    mfma_tile(As, Bs, lane, wm, wn, acc);
    __syncthreads();
  }
  int rbase = tm * 128 + wm * 64;
#pragma unroll
  for (int ni = 0; ni < 4; ++ni) {
    int col = n0 + wn * 64 + ni * 16 + (lane & 15);
    float bias = b2[e * DM + col];
#pragma unroll
    for (int mi = 0; mi < 4; ++mi) {
#pragma unroll
      for (int r = 0; r < 4; ++r) {
        int row = rbase + mi * 16 + (lane >> 4) * 4 + r;
        eo[(size_t)row * DM + col] = acc[mi][ni][r] + bias;
      }
    }
  }
}

// ---------------- combine: gate-weighted sum + pooled mean -------------------
__global__ __launch_bounds__(256)
void combine_kernel(const float* __restrict__ eo, const int* __restrict__ slots,
                    const float* __restrict__ top2w, float* __restrict__ pooled,
                    float* __restrict__ combined) {
  int b = blockIdx.x, t = threadIdx.x;
  int s0 = slots[b * 2], s1 = slots[b * 2 + 1];
  float w0 = top2w[b * 2], w1 = top2w[b * 2 + 1];
  float px = 0, py = 0, pz = 0, pw = 0;
#pragma unroll
  for (int m = 0; m < 4; ++m) {
    float4 a = ((const float4*)(eo + (size_t)(s0 * 4 + m) * DM))[t];
    float4 c = ((const float4*)(eo + (size_t)(s1 * 4 + m) * DM))[t];
    float4 v;
    v.x = w0 * a.x + w1 * c.x;
    v.y = w0 * a.y + w1 * c.y;
    v.z = w0 * a.z + w1 * c.z;
    v.w = w0 * a.w + w1 * c.w;
    ((float4*)(combined + ((size_t)b * NM + m) * DM))[t] = v;
    px += v.x; py += v.y; pz += v.z; pw += v.w;
  }
  float4 pv; pv.x = px * 0.25f; pv.y = py * 0.25f; pv.z = pz * 0.25f; pv.w = pw * 0.25f;
  ((float4*)(pooled + (size_t)b * DM))[t] = pv;
}

// ---------------- balance loss ----------------------------------------------
__global__ __launch_bounds__(256)
void balance_kernel(const float* __restrict__ gates, const int* __restrict__ counts,
                    float* __restrict__ out_bal) {
  int t = threadIdx.x;
  float imp[8] = {0, 0, 0, 0, 0, 0, 0, 0};
  for (int b = t; b < NB; b += 256) {
#pragma unroll
    for (int e = 0; e < 8; ++e) imp[e] += gates[b * 8 + e];
  }
  __shared__ float red[256];
  __shared__ float impE[8];
  for (int e = 0; e < 8; ++e) {
    red[t] = imp[e];
    __syncthreads();
    for (int s = 128; s > 0; s >>= 1) { if (t < s) red[t] += red[t + s]; __syncthreads(); }
    if (t == 0) impE[e] = red[0];
    __syncthreads();
  }
  if (t == 0) {
    float mi = 0, ml = 0;
    for (int e = 0; e < 8; ++e) { mi += impE[e]; ml += (float)counts[e]; }
    mi *= 0.125f; ml *= 0.125f;
    float vi = 0, vl = 0;
    for (int e = 0; e < 8; ++e) {
      float di = impE[e] - mi, dl = (float)counts[e] - ml;
      vi += di * di; vl += dl * dl;
    }
    vi *= (1.f / 7.f); vl *= (1.f / 7.f);           // ddof=1
    float cvi = vi / (mi * mi + 1e-10f);
    float cvl = vl / (ml * ml + 1e-10f);
    out_bal[0] = 0.01f * (cvi + cvl);
  }
}

// ---------------- host launch ------------------------------------------------
extern "C" void kernel_launch(void* const* d_in, const int* in_sizes, int n_in,
                              void* d_out, int out_size, void* d_ws, size_t ws_size,
                              hipStream_t stream) {
  (void)in_sizes; (void)n_in; (void)out_size; (void)ws_size;
  const float* xin[4] = {(const float*)d_in[0], (const float*)d_in[3],
                         (const float*)d_in[6], (const float*)d_in[9]};
  const float* win[4] = {(const float*)d_in[1], (const float*)d_in[4],
                         (const float*)d_in[7], (const float*)d_in[10]};
  const float* bpin[4] = {(const float*)d_in[2], (const float*)d_in[5],
                          (const float*)d_in[8], (const float*)d_in[11]};
  const int Ks[4] = {768, 1536, 512, 2048};
  const float* ln_g = (const float*)d_in[12];
  const float* ln_b = (const float*)d_in[13];
  const float* Wg = (const float*)d_in[14];
  const float* bg = (const float*)d_in[15];
  const float* W1 = (const float*)d_in[16];
  const float* b1 = (const float*)d_in[17];
  const float* W2 = (const float*)d_in[18];
  const float* b2 = (const float*)d_in[19];

  char* p = (char*)d_ws;
  auto take = [&](size_t n) { char* r = p; p += (n + 255) & ~(size_t)255; return r; };
  __hip_bfloat16* W1T = (__hip_bfloat16*)take((size_t)NE * NH * DM * 2);
  __hip_bfloat16* W2T = (__hip_bfloat16*)take((size_t)NE * NH * DM * 2);
  float* tokens = (float*)take((size_t)NB * NM * DM * 4);
  __hip_bfloat16* tokbf = (__hip_bfloat16*)take((size_t)NB * NM * DM * 2);
  __hip_bfloat16* hbuf = (__hip_bfloat16*)take((size_t)CAPP * 4 * NH * 2);
  float* eo = (float*)take((size_t)CAPP * 4 * DM * 4);
  int* top2i = (int*)take(NB * 2 * 4);
  float* top2w = (float*)take(NB * 2 * 4);
  int* slots = (int*)take(NB * 2 * 4);
  int* pair_b = (int*)take(CAPP * 4);
  int* tile_e = (int*)take(NTIL * 4);
  int* counts = (int*)take(64);
  int* fill = (int*)take(64);
  int* offs = (int*)take(64);

  // XS/WT alias hbuf (dead until gemm1, which runs after proj_mfma)
  unsigned short* scratch = (unsigned short*)hbuf;
  ProjMArgs pm;
  SplitArgs sa;
  {
    unsigned short* q = scratch;
    for (int z = 0; z < 4; ++z) { pm.xs[z] = q; sa.xs[z] = q; q += (size_t)NB * 2 * Ks[z]; }
    for (int z = 0; z < 4; ++z) { pm.wt[z] = q; sa.wt[z] = q; q += (size_t)DM * 2 * Ks[z]; }
    for (int z = 0; z < 4; ++z) {
      pm.bp[z] = bpin[z]; pm.K[z] = Ks[z];
      sa.x[z] = xin[z]; sa.w[z] = win[z]; sa.K[z] = Ks[z];
    }
  }

  float* out = (float*)d_out;
  float* out_pooled = out;                    // [2048][1024]
  float* out_combined = out + 2097152;        // [2048][4][1024]
  float* out_gates = out + 10485760;          // [2048][8]
  float* out_bal = out + 10502144;            // scalar

  init_kernel<<<dim3(17), dim3(256), 0, stream>>>(counts, fill, pair_b);
  split_x_all_kernel<<<dim3(4096, 4), dim3(256), 0, stream>>>(sa);
  split_w_all_kernel<<<dim3(32, 64, 4), dim3(256), 0, stream>>>(sa);
  transpose_bf_kernel<<<dim3(64, 16, 8), dim3(256), 0, stream>>>(W1, W1T, 1024, 4096);
  transpose_bf_kernel<<<dim3(16, 64, 8), dim3(256), 0, stream>>>(W2, W2T, 4096, 1024);
  proj_mfma_kernel<<<dim3(8, 64), dim3(256), 0, stream>>>(pm, tokens);
  ln_router_kernel<<<dim3(NB), dim3(256), 0, stream>>>(tokens, tokbf, ln_g, ln_b, Wg, bg,
                                                       out_gates, top2i, top2w, counts);
  offsets_kernel<<<dim3(1), dim3(256), 0, stream>>>(counts, offs, tile_e);
  fill_kernel<<<dim3(8), dim3(256), 0, stream>>>(top2i, fill, offs, pair_b, slots);
  gemm1_kernel<<<dim3(32, NTIL), dim3(256), 0, stream>>>(tokbf, W1T, b1, pair_b, tile_e, hbuf);
  gemm2_kernel<<<dim3(8, NTIL), dim3(256), 0, stream>>>(hbuf, W2T, b2, tile_e, eo);
  combine_kernel<<<dim3(NB), dim3(256), 0, stream>>>(eo, slots, top2w, out_pooled, out_combined);
  balance_kernel<<<dim3(1), dim3(256), 0, stream>>>(out_gates, counts, out_bal);
}